// Round 14
// baseline (657.448 us; speedup 1.0000x reference)
//
#include <hip/hip_runtime.h>

// F2FConv3d on MI355X.
// V15 = 32x32 amortization (V14) at 3 waves/SIMD (V6 occupancy) via K-SPLIT WAVE PAIRS.
// Waves = (wc = channel half, wk = K half). Each wave: 18 of the 36 K-chunks
// (c = 2*cc + wk) -> wf = 72 AGPRs (V6 footprint, fits (256,3)); computes a PARTIAL
// 32ch x 32tex tile over its K-half; pair (wc,0)+(wc,1) sums partials through a 2KB
// LDS exchange (conflict-free b128 lane*16 layout, +1 barrier). The split also halves
// per-wave X needs (4 ds_read_b128, 8 pkrtz) and B-build (72 pk_mul vs 144).
//
// Block-iter = 2 groups (32 tex). Pipeline = V6 verbatim: 3-buffer rotation, stage(t)
// targets buffer read at t-1, depth-2 counted vmcnt ([stage:5][stores:2], steady
// WAITV(9), never 0 in loop), X via global_load_lds (linear dest, swizzled global
// src: LDS[tt][g] = X[tt][g ^ (tt&15)] -> conflict-free swizzled b128 reads).
//
// A-frag layout (verified by V14 passing): chunk c: o = wc*32 + (lane&31),
// i = (c&3)*16 + (lane>>5)*8 + j, kb = c>>2. C/D (m74/m101): col = lane&31 (tex),
// row = (reg&3) + 8*(reg>>2) + 4*(lane>>5). Facet = 4 adjacent lanes -> DPP qsum.
// Wave EPIs reg-half wk (rows -> ch = wc*32 + wk*16 + {0,8} + 4hi + j); writes its
// non-EPI half to xchg slot [wc][wk]; reads partner slot [wc][1-wk]. Stats exact
// (lane q = lane&3 takes disjoint channel slices; no overcount).

typedef _Float16 half8  __attribute__((ext_vector_type(8)));
typedef _Float16 h2     __attribute__((ext_vector_type(2)));
typedef __fp16   fp16x2 __attribute__((ext_vector_type(2)));
typedef float    f32x4  __attribute__((ext_vector_type(4)));
typedef float    f32x16 __attribute__((ext_vector_type(16)));

#define NPAIRS  50000    // group pairs (32 tex per block-iter)
#define FFACETS 400000
#define GRID1   768      // 3 blocks/CU x 256 CUs, exactly resident
#define LDSP    9472     // per buffer: X[0,8192) | BARY[8192,9344) | NTEX[9344,9376)

#define WAITV(N) asm volatile("s_waitcnt vmcnt(" #N ")" ::: "memory")
#define WAITL0() asm volatile("s_waitcnt lgkmcnt(0)" ::: "memory")
#define FENCE()  asm volatile("" ::: "memory")

union H8 { h2 h[4]; half8 v; };

static __device__ __forceinline__ h2 pkrtz(float a, float b) {
    fp16x2 r = __builtin_amdgcn_cvt_pkrtz(a, b);
    return __builtin_bit_cast(h2, r);
}

// facet sum over the 4 adjacent lanes of a quad — VALU-pipe DPP, no DS traffic
static __device__ __forceinline__ float qsum(float s) {
    s += __builtin_bit_cast(float, __builtin_amdgcn_mov_dpp(
             __builtin_bit_cast(int, s), 0xB1, 0xF, 0xF, true));   // quad_perm [1,0,3,2]
    s += __builtin_bit_cast(float, __builtin_amdgcn_mov_dpp(
             __builtin_bit_cast(int, s), 0x4E, 0xF, 0xF, true));   // quad_perm [2,3,0,1]
    return s;
}

static __device__ __forceinline__ void gload16(const void* g, void* l) {
    __builtin_amdgcn_global_load_lds((const __attribute__((address_space(1))) void*)g,
                                     (__attribute__((address_space(3))) void*)l, 16, 0, 0);
}

// ---- kernel 1: swizzle W (fp32 [64][64][9]) -> 32x32x16 A-fragment order, zero stats
__global__ __launch_bounds__(256) void prep_kernel(const float* __restrict__ W,
                                                   _Float16* __restrict__ wswz,
                                                   float* __restrict__ stats) {
    int idx = blockIdx.x * 256 + threadIdx.x;
    if (idx < 36864) {
        int j    = idx & 7;
        int lane = (idx >> 3) & 63;
        int wc   = (idx >> 9) & 1;        // channel half
        int c    = idx >> 10;             // chunk 0..35
        int o    = wc * 32 + (lane & 31);
        int i    = (c & 3) * 16 + (lane >> 5) * 8 + j;
        int kb   = c >> 2;
        wswz[idx] = (_Float16)W[(o * 64 + i) * 9 + kb];
    }
    if (idx < 128) stats[idx] = 0.0f;
}

// ---- kernel 2: fused GEMM + facet mean + bias + ReLU + BN-stat accumulation
__global__ __launch_bounds__(256, 3) void pass1_kernel(
    const float* __restrict__ X, const float* __restrict__ BARY,
    const _Float16* __restrict__ WSWZ, const float* __restrict__ BIAS,
    const int* __restrict__ NTEX, float* __restrict__ OUT,
    float* __restrict__ stats) {

    __shared__ __align__(16) char ldsbuf[3 * LDSP];
    __shared__ __align__(16) char xchg[8192];     // 4 slots x 2KB: [wc][wk][2 planes][64 lanes x 16B]
    __shared__ float sl_s[64];
    __shared__ float sl_s2[64];

    const int tid  = threadIdx.x;
    const int wave = tid >> 6;
    const int lane = tid & 63;
    const int wc   = wave >> 1;   // channel half (ch 0-31 / 32-63)
    const int wk   = wave & 1;    // K half (chunks c with c&1 == wk)
    const int t    = lane & 31;   // texture (MFMA column)
    const int hi   = lane >> 5;

    // A-operand: 18 chunks (c = 2*cc+wk) x 4 VGPR = 72 AGPRs, resident whole kernel
    half8 wf[18];
#pragma unroll
    for (int cc = 0; cc < 18; ++cc)
        wf[cc] = *(const half8*)(WSWZ + ((size_t)((2 * cc + wk) * 2 + wc) * 64 + lane) * 8);

    // bias for this wave's 8 channels: planes pp=0,1 -> ch = wc*32 + wk*16 + pp*8 + 4hi + j
    const f32x4 bias0 = *(const f32x4*)(BIAS + wc * 32 + wk * 16 + 4 * hi);
    const f32x4 bias1 = *(const f32x4*)(BIAS + wc * 32 + wk * 16 + 8 + 4 * hi);

    // ---- stage-side: linear LDS dest, swizzled global src (LDS[tt][g] = X[tt][g^(tt&15)])
    int xsg[2], xdd[2];
#pragma unroll
    for (int i = 0; i < 2; ++i) {
        const int tt = wave * 8 + i * 4 + (lane >> 4);
        xsg[i] = tt * 256 + (((lane & 15) ^ (tt & 15)) << 4);
        xdd[i] = wave * 2048 + i * 1024 + lane * 16;
    }
    const char* Xb  = (const char*)X;
    const char* BAb = (const char*)BARY;
    const char* NTb = (const char*)NTEX;

    // ---- read-side: wave needs quarters {wk, wk+2}; per quarter, hi's 2 granules
    int xr[4];
#pragma unroll
    for (int g = 0; g < 4; ++g) {                 // g = qsel*2 + jj
        const int gg = (wk + 2 * (g >> 1)) * 4 + hi * 2 + (g & 1);
        xr[g] = t * 256 + ((gg ^ (t & 15)) << 4);
    }
    const int bco = 8192 + t * 36;                // 32 distinct banks (9 coprime 32)
    const int nco = 9344 + ((t >> 2) << 2);

    float sacc0 = 0.f, s2acc0 = 0.f, sacc1 = 0.f, s2acc1 = 0.f;

    const int b = blockIdx.x;
    const int n = (NPAIRS - 1 - b) / GRID1 + 1;   // pairs for this block (uniform)

    // 5 vmem ops per wave per STAGE (uniform across waves)
    auto STAGE = [&](char* S, int u) {
        const char* xs = Xb + (size_t)u * 8192;
        FENCE();
        gload16(xs + xsg[0], S + xdd[0]);
        gload16(xs + xsg[1], S + xdd[1]);
        gload16(BAb + (size_t)u * 1152 + lane * 16, S + 8192 + lane * 16);
        if (lane < 8) gload16(BAb + (size_t)u * 1152 + 1024 + lane * 16, S + 9216 + lane * 16);
        if (lane < 2) gload16(NTb + (size_t)u * 32 + lane * 16,          S + 9344 + lane * 16);
        FENCE();
    };

    // ITER: [BAR_A][read L: 4 b128 X + 9 b32 bary + nt][stage into S][pack][18 MFMA]
    //       [write non-EPI half -> xchg][lgkm0][BAR_B][read partner half][EPI + 2 stores]
    // BAR_A separates iter-t xchg reads from iter-t+1 xchg writes (slot reuse safe).
    auto ITER = [&](const char* L, char* S, int u, int upre, bool do_stage) {
        __builtin_amdgcn_s_barrier();      // BAR_A: caller did WAITV -> stage(u) landed
        FENCE();
        f32x4 r[4];
#pragma unroll
        for (int g = 0; g < 4; ++g) r[g] = *(const f32x4*)(L + xr[g]);
        float bF[9];
#pragma unroll
        for (int k = 0; k < 9; ++k) bF[k] = *(const float*)(L + bco + k * 4);
        const int nt = *(const int*)(L + nco);

        if (do_stage) STAGE(S, upre);      // issued early; flies across 2 iterations

        // pack this wave's x quarters (8 pkrtz) and bary (9 pkrtz)
        h2 xh[8], bh[9];
#pragma unroll
        for (int g = 0; g < 4; ++g) {
            xh[g * 2]     = pkrtz(r[g][0], r[g][1]);
            xh[g * 2 + 1] = pkrtz(r[g][2], r[g][3]);
        }
#pragma unroll
        for (int k = 0; k < 9; ++k) bh[k] = pkrtz(bF[k], bF[k]);
        const float rc = __builtin_amdgcn_rcpf((float)nt);   // exact for pow2 counts

        // ---- 18 MFMAs, single 16-reg accumulator chain (partial over this K-half)
        f32x16 acc = {};
        __builtin_amdgcn_s_setprio(1);
#pragma unroll
        for (int cc = 0; cc < 18; ++cc) {
            const h2 bk = bh[cc >> 1];             // kb = (2cc+wk)>>2 = cc>>1
            const int bs = (cc & 1) * 4;           // quarter select: wk / wk+2
            H8 bf;
            bf.h[0] = xh[bs + 0] * bk;  bf.h[1] = xh[bs + 1] * bk;
            bf.h[2] = xh[bs + 2] * bk;  bf.h[3] = xh[bs + 3] * bk;
            acc = __builtin_amdgcn_mfma_f32_32x32x16_f16(wf[cc], bf.v, acc, 0, 0, 0);
        }
        __builtin_amdgcn_s_setprio(0);

        // ---- cross-wave exchange: write non-EPI half, read partner's (wk uniform branch)
        f32x4 wlo, whi, mlo, mhi;
        if (wk == 0) {
            wlo = (f32x4){acc[8],  acc[9],  acc[10], acc[11]};
            whi = (f32x4){acc[12], acc[13], acc[14], acc[15]};
            mlo = (f32x4){acc[0],  acc[1],  acc[2],  acc[3]};
            mhi = (f32x4){acc[4],  acc[5],  acc[6],  acc[7]};
        } else {
            wlo = (f32x4){acc[0],  acc[1],  acc[2],  acc[3]};
            whi = (f32x4){acc[4],  acc[5],  acc[6],  acc[7]};
            mlo = (f32x4){acc[8],  acc[9],  acc[10], acc[11]};
            mhi = (f32x4){acc[12], acc[13], acc[14], acc[15]};
        }
        char* slotW = xchg + (size_t)(wc * 2 + wk) * 2048;
        *(f32x4*)(slotW + lane * 16)        = wlo;
        *(f32x4*)(slotW + 1024 + lane * 16) = whi;
        WAITL0();
        __builtin_amdgcn_s_barrier();      // BAR_B: partner halves visible
        FENCE();
        const char* slotR = xchg + (size_t)(wc * 2 + (1 - wk)) * 2048;
        f32x4 plo = *(const f32x4*)(slotR + lane * 16);
        f32x4 phi = *(const f32x4*)(slotR + 1024 + lane * 16);

        // ---- facet mean + bias + ReLU (rows: ch = wc*32 + wk*16 + pp*8 + 4hi + j)
        const int f = u * 8 + (t >> 2);
        f32x4 vq0, vq1;
#pragma unroll
        for (int j = 0; j < 4; ++j) {
            float s0 = qsum(mlo[j] + plo[j]);
            float s1 = qsum(mhi[j] + phi[j]);
            s0 = s0 * rc + bias0[j];
            s1 = s1 * rc + bias1[j];
            vq0[j] = s0 > 0.f ? s0 : 0.f;
            vq1[j] = s1 > 0.f ? s1 : 0.f;
        }
        // stats: lane q takes slice j==q of each plane (disjoint -> exact, no overcount)
        {
            const int q = lane & 3;
            float p0 = vq0[0]; p0 = (q == 1) ? vq0[1] : p0;
            p0 = (q == 2) ? vq0[2] : p0;  p0 = (q == 3) ? vq0[3] : p0;
            float p1 = vq1[0]; p1 = (q == 1) ? vq1[1] : p1;
            p1 = (q == 2) ? vq1[2] : p1;  p1 = (q == 3) ? vq1[3] : p1;
            sacc0 += p0;  s2acc0 += p0 * p0;
            sacc1 += p1;  s2acc1 += p1 * p1;
        }
        if ((lane & 3) == 0) {
            float* op = OUT + (size_t)f * 64 + wc * 32 + wk * 16 + 4 * hi;
            *(f32x4*)(op)     = vq0;
            *(f32x4*)(op + 8) = vq1;
        }
    };

    char* B0 = ldsbuf;
    char* B1 = ldsbuf + LDSP;
    char* B2 = ldsbuf + 2 * LDSP;

    // ---- software pipeline: 3-buffer rotation, counted vmcnt ([stage:5][stores:2])
    STAGE(B0, b);
    STAGE(B1, b + GRID1);
    WAITV(5); ITER(B0, B2, b,         b + 2 * GRID1, true);   // drains wf/bias prologue loads
    WAITV(7); ITER(B1, B0, b + GRID1, b + 3 * GRID1, true);
    char *rd = B2, *st = B1, *ot = B0;
    int tI = 2;
    for (; tI < n - 2; ++tI) {
        WAITV(9);
        ITER(rd, st, b + tI * GRID1, b + (tI + 2) * GRID1, true);
        char* tmp = ot; ot = st; st = rd; rd = tmp;
    }
    WAITV(9); ITER(rd, st, b + tI * GRID1, 0, false);
    { char* tmp = ot; ot = st; st = rd; rd = tmp; } ++tI;
    WAITV(4); ITER(rd, st, b + tI * GRID1, 0, false);

    // ---- stats: reduce the 8 facet-quads (lane bits 2-4), write disjoint channels
    {
        float s0 = sacc0, q0 = s2acc0, s1 = sacc1, q1 = s2acc1;
        s0 += __shfl_xor(s0, 4);  s0 += __shfl_xor(s0, 8);  s0 += __shfl_xor(s0, 16);
        q0 += __shfl_xor(q0, 4);  q0 += __shfl_xor(q0, 8);  q0 += __shfl_xor(q0, 16);
        s1 += __shfl_xor(s1, 4);  s1 += __shfl_xor(s1, 8);  s1 += __shfl_xor(s1, 16);
        q1 += __shfl_xor(q1, 4);  q1 += __shfl_xor(q1, 8);  q1 += __shfl_xor(q1, 16);
        if ((lane & 28) == 0) {
            const int ch0 = wc * 32 + wk * 16 + 4 * hi + (lane & 3);
            sl_s [ch0]     = s0;  sl_s2[ch0]     = q0;
            sl_s [ch0 + 8] = s1;  sl_s2[ch0 + 8] = q1;
        }
    }
    __syncthreads();
    if (tid < 64)        atomicAdd(&stats[tid],      sl_s [tid]);
    else if (tid < 128)  atomicAdd(&stats[tid],      sl_s2[tid - 64]);
}

// ---- kernel 3: in-place batch-norm normalize on OUT
__global__ __launch_bounds__(256) void pass3_kernel(float* __restrict__ OUT,
    const float* __restrict__ stats, const float* __restrict__ gamma,
    const float* __restrict__ beta) {
    const int tid = threadIdx.x;
    const size_t l = (size_t)blockIdx.x * 256 + tid;
    const int c0 = ((int)l & 15) * 4;     // grid*256 is a multiple of 16 -> constant per thread
    float mu[4], sc[4], be[4];
    const float invF = 1.0f / (float)FFACETS;
#pragma unroll
    for (int u = 0; u < 4; ++u) {
        int ch = c0 + u;
        float m  = stats[ch] * invF;
        float va = stats[64 + ch] * invF - m * m;
        mu[u] = m;
        sc[u] = rsqrtf(va + 1e-3f) * gamma[ch];
        be[u] = beta[ch];
    }
    const size_t n4 = (size_t)FFACETS * 16;
    for (size_t i = l; i < n4; i += (size_t)gridDim.x * 256) {
        f32x4 v = ((f32x4*)OUT)[i];
#pragma unroll
        for (int u = 0; u < 4; ++u)
            v[u] = (v[u] - mu[u]) * sc[u] + be[u];
        ((f32x4*)OUT)[i] = v;
    }
}

extern "C" void kernel_launch(void* const* d_in, const int* in_sizes, int n_in,
                              void* d_out, int out_size, void* d_ws, size_t ws_size,
                              hipStream_t stream) {
    const float* X     = (const float*)d_in[0];
    const float* BARY  = (const float*)d_in[1];
    const float* W     = (const float*)d_in[2];
    const float* BIAS  = (const float*)d_in[3];
    const float* GAMMA = (const float*)d_in[4];
    const float* BETA  = (const float*)d_in[5];
    const int*   NTEX  = (const int*)d_in[6];
    float* OUT = (float*)d_out;

    _Float16* wswz = (_Float16*)d_ws;                       // 73728 B
    float* stats   = (float*)((char*)d_ws + 73728);         // 128 floats

    prep_kernel<<<144, 256, 0, stream>>>(W, wswz, stats);
    pass1_kernel<<<GRID1, 256, 0, stream>>>(X, BARY, wswz, BIAS, NTEX, OUT, stats);
    pass3_kernel<<<2048, 256, 0, stream>>>(OUT, stats, GAMMA, BETA);
}